// Round 8
// baseline (3102.605 us; speedup 1.0000x reference)
//
#include <hip/hip_runtime.h>
#include <math.h>

#define SEQT 2048
#define BATCH 256
#define INDIM 64
#define HDIM 128

typedef float v2f __attribute__((ext_vector_type(2)));

// ---- fast branch-free erf (Abramowitz-Stegun 7.1.26, |abs err| <= 1.5e-7) ----
// gelu(x) = 0.5*x + 0.5*|x|*erf(|x|/sqrt2)
__device__ __forceinline__ float gelu_fast(float x) {
    const float ax = __builtin_fabsf(x);
    const float z  = ax * 0.70710678118654752f;
    const float t  = __builtin_amdgcn_rcpf(__builtin_fmaf(0.3275911f, z, 1.0f));
    float p = __builtin_fmaf(1.061405429f, t, -1.453152027f);
    p = __builtin_fmaf(p, t, 1.421413741f);
    p = __builtin_fmaf(p, t, -0.284496736f);
    p = __builtin_fmaf(p, t, 0.254829592f);
    p = p * t;
    const float e = __builtin_amdgcn_exp2f(z * z * -1.44269504088896f);
    const float erfv = __builtin_fmaf(-p, e, 1.0f);
    return __builtin_fmaf(0.5f * ax, erfv, 0.5f * x);
}

__device__ __forceinline__ v2f gelu2(v2f s) {
    v2f r;
    r.x = gelu_fast(s.x);
    r.y = gelu_fast(s.y);
    return r;
}

// ---- packed FMA with explicit word-broadcast of src1 (no splat movs) ----
__device__ __forceinline__ void pk_lo(v2f& acc, v2f w, v2f hp) {
    asm("v_pk_fma_f32 %0, %1, %2, %0 op_sel:[0,0,0] op_sel_hi:[1,0,1]"
        : "+v"(acc) : "v"(w), "v"(hp));
}
__device__ __forceinline__ void pk_hi(v2f& acc, v2f w, v2f hp) {
    asm("v_pk_fma_f32 %0, %1, %2, %0 op_sel:[0,1,0] op_sel_hi:[1,1,1]"
        : "+v"(acc) : "v"(w), "v"(hp));
}

// 128-K dot, 2 outputs per lane: 64 uniform ds_read_b64 (HW broadcast) +
// exactly 128 v_pk_fma_f32. 8 accumulators keep dep chains short.
__device__ __forceinline__ v2f dot128(const v2f* __restrict__ w2, const float* hsrc) {
    v2f a0 = {0.f,0.f}, a1 = {0.f,0.f}, a2 = {0.f,0.f}, a3 = {0.f,0.f};
    v2f a4 = {0.f,0.f}, a5 = {0.f,0.f}, a6 = {0.f,0.f}, a7 = {0.f,0.f};
    #pragma unroll
    for (int j = 0; j < 128; j += 8) {
        v2f p0 = *reinterpret_cast<const v2f*>(&hsrc[j]);
        v2f p1 = *reinterpret_cast<const v2f*>(&hsrc[j + 2]);
        v2f p2 = *reinterpret_cast<const v2f*>(&hsrc[j + 4]);
        v2f p3 = *reinterpret_cast<const v2f*>(&hsrc[j + 6]);
        pk_lo(a0, w2[j],     p0);  pk_hi(a1, w2[j + 1], p0);
        pk_lo(a2, w2[j + 2], p1);  pk_hi(a3, w2[j + 3], p1);
        pk_lo(a4, w2[j + 4], p2);  pk_hi(a5, w2[j + 5], p2);
        pk_lo(a6, w2[j + 6], p3);  pk_hi(a7, w2[j + 7], p3);
    }
    return ((a0 + a1) + (a2 + a3)) + ((a4 + a5) + (a6 + a7));
}

// 64-K dot (xin0 path)
__device__ __forceinline__ v2f dot64(const v2f* __restrict__ w2, const float* hsrc) {
    v2f a0 = {0.f,0.f}, a1 = {0.f,0.f}, a2 = {0.f,0.f}, a3 = {0.f,0.f};
    #pragma unroll
    for (int j = 0; j < 64; j += 4) {
        v2f p0 = *reinterpret_cast<const v2f*>(&hsrc[j]);
        v2f p1 = *reinterpret_cast<const v2f*>(&hsrc[j + 2]);
        pk_lo(a0, w2[j],     p0);  pk_hi(a1, w2[j + 1], p0);
        pk_lo(a2, w2[j + 2], p1);  pk_hi(a3, w2[j + 3], p1);
    }
    return (a0 + a1) + (a2 + a3);
}

// One workgroup per batch row. 256 threads = 4 waves, 1 wave/SIMD.
// Each wave owns ONE FULL matrix in registers (w2[128] v2f = 256 VGPR,
// legal at 1 wave/SIMD with the 512-reg unified file):
//   wv0: rec0  s=t-2: h0[s] = gelu(Wh0 @ h0[s-1] + xin0[s])       (in-wave chain)
//   wv1: rec1  r=t-4: h1[r] = gelu(Wh1 @ h1[r-1] + xin1[r]); y1 store
//   wv2: xin1  u=t-3: Win1 @ h0[u]
//   wv3: xin0      t: Win0 @ x[t]; x staging (lag-2 prefetch)
// Recurrence is wave-private (own ring slot write -> read next iter, no
// cross-wave combine); barrier only orders the LAGGED feeds. Rings depth-4.
__global__ __launch_bounds__(256, 1)
__attribute__((amdgpu_waves_per_eu(1, 1)))
void rnn_scan_kernel(
    const float* __restrict__ seq,
    const float* __restrict__ Win0, const float* __restrict__ Wh0,
    const float* __restrict__ Win1, const float* __restrict__ Wh1,
    const float* __restrict__ h00, const float* __restrict__ h01,
    float* __restrict__ out)
{
    const int b = blockIdx.x;
    const int tid = threadIdx.x;
    const int wv = tid >> 6;
    const int l = tid & 63;

    __shared__ __align__(16) float h0ring[4][HDIM];   // h0 history (uniform-read)
    __shared__ __align__(16) float h1ring[4][HDIM];   // h1 history (wv1 private)
    __shared__ __align__(16) v2f   p1ring[4][64];     // xin1 results
    __shared__ __align__(16) v2f   x0ring[4][64];     // xin0 results
    __shared__ __align__(16) float xring[4][INDIM];   // staged x

    // ---- full weight matrix per wave: rows 2l, 2l+1 interleaved as float2 ----
    v2f w2[128];
    if (wv < 3) {
        const float* W = (wv == 0) ? Wh0 : (wv == 1) ? Wh1 : Win1;
        const float* ra = &W[(2 * l) * HDIM];
        const float* rb = &W[(2 * l + 1) * HDIM];
        #pragma unroll
        for (int j = 0; j < 128; j += 4) {
            float4 a = *reinterpret_cast<const float4*>(&ra[j]);
            float4 bq = *reinterpret_cast<const float4*>(&rb[j]);
            w2[j]     = (v2f){a.x, bq.x};
            w2[j + 1] = (v2f){a.y, bq.y};
            w2[j + 2] = (v2f){a.z, bq.z};
            w2[j + 3] = (v2f){a.w, bq.w};
        }
    } else {
        const float* ra = &Win0[(2 * l) * INDIM];
        const float* rb = &Win0[(2 * l + 1) * INDIM];
        #pragma unroll
        for (int j = 0; j < 64; j += 4) {
            float4 a = *reinterpret_cast<const float4*>(&ra[j]);
            float4 bq = *reinterpret_cast<const float4*>(&rb[j]);
            w2[j]     = (v2f){a.x, bq.x};
            w2[j + 1] = (v2f){a.y, bq.y};
            w2[j + 2] = (v2f){a.z, bq.z};
            w2[j + 3] = (v2f){a.w, bq.w};
        }
    }

    // ---- prologue: init states into ring slot 3 (= slot (-1)&3), x staging ----
    float xA = 0.f, xB = 0.f;
    if (wv == 0) {
        *reinterpret_cast<v2f*>(&h0ring[3][2 * l]) = *reinterpret_cast<const v2f*>(&h00[2 * l]);
    } else if (wv == 1) {
        *reinterpret_cast<v2f*>(&h1ring[3][2 * l]) = *reinterpret_cast<const v2f*>(&h01[2 * l]);
    } else if (wv == 3) {
        const size_t base = (size_t)b * INDIM + l;
        xring[0][l] = seq[base];
        xring[1][l] = seq[(size_t)1 * BATCH * INDIM + base];
        xA          = seq[(size_t)2 * BATCH * INDIM + base];
        xB          = seq[(size_t)3 * BATCH * INDIM + base];
    }
    __syncthreads();

    const size_t YSZ = (size_t)SEQT * BATCH * HDIM;

    for (int t = 0; t <= SEQT + 3; ++t) {
        if (wv == 0) {
            // ---- rec0: s = t-2 ----
            const int s = t - 2;
            if (s >= 0 && s <= SEQT - 1) {
                v2f acc = dot128(w2, h0ring[(s - 1) & 3]);       // Wh0 @ h0[s-1]
                v2f h2 = gelu2(acc + x0ring[s & 3][l]);          // h0[s]
                *reinterpret_cast<v2f*>(&h0ring[s & 3][2 * l]) = h2;
                if (s == SEQT - 1)
                    *reinterpret_cast<v2f*>(&out[YSZ + (size_t)b * HDIM + 2 * l]) = h2;
            }
        } else if (wv == 1) {
            // ---- rec1: r = t-4 ----
            const int r = t - 4;
            if (r >= 0 && r <= SEQT - 1) {
                v2f acc = dot128(w2, h1ring[(r - 1) & 3]);       // Wh1 @ h1[r-1]
                v2f h2 = gelu2(acc + p1ring[r & 3][l]);          // h1[r]
                *reinterpret_cast<v2f*>(&h1ring[r & 3][2 * l]) = h2;
                *reinterpret_cast<v2f*>(&out[((size_t)r * BATCH + b) * HDIM + 2 * l]) = h2;
                if (r == SEQT - 1)
                    *reinterpret_cast<v2f*>(
                        &out[YSZ + (size_t)BATCH * HDIM + (size_t)b * HDIM + 2 * l]) = h2;
            }
        } else if (wv == 2) {
            // ---- xin1: u = t-3 ----
            const int u = t - 3;
            if (u >= 0 && u <= SEQT - 1) {
                p1ring[u & 3][l] = dot128(w2, h0ring[u & 3]);    // Win1 @ h0[u]
            }
        } else {
            // ---- xin0 + x staging ----
            if (t <= SEQT - 1) {
                x0ring[t & 3][l] = dot64(w2, xring[t & 3]);      // Win0 @ x[t]
                if (t + 2 <= SEQT - 1) {
                    xring[(t + 2) & 3][l] = xA;                  // x[t+2] (issued 2 iters ago)
                    xA = xB;
                    int tn = t + 4; if (tn > SEQT - 1) tn = SEQT - 1;
                    xB = seq[(size_t)tn * BATCH * INDIM + (size_t)b * INDIM + l];
                }
            }
        }
        __syncthreads();
    }
}

extern "C" void kernel_launch(void* const* d_in, const int* in_sizes, int n_in,
                              void* d_out, int out_size, void* d_ws, size_t ws_size,
                              hipStream_t stream) {
    const float* seq  = (const float*)d_in[0];
    const float* Win0 = (const float*)d_in[1];
    const float* Wh0  = (const float*)d_in[2];
    const float* Win1 = (const float*)d_in[3];
    const float* Wh1  = (const float*)d_in[4];
    const float* h00  = (const float*)d_in[5];
    const float* h01  = (const float*)d_in[6];

    rnn_scan_kernel<<<dim3(BATCH), dim3(256), 0, stream>>>(
        seq, Win0, Wh0, Win1, Wh1, h00, h01, (float*)d_out);
}